// Round 3
// baseline (75.975 us; speedup 1.0000x reference)
//
#include <hip/hip_runtime.h>
#include <hip/hip_bf16.h>

#define NB 128          // tracklets (b)
#define NS 32           // frames per tracklet (s)
#define DF 256          // feature dim
#define NROW (NB*NS)    // 4096
#define KSTEPS (DF/16)  // 16 MFMA k-steps of 16
#define MARGIN 0.3f
#define PANEL (KSTEPS*64)   // bf16x8 slots per tracklet panel

typedef short bf16x8 __attribute__((ext_vector_type(8)));
typedef short bf16x4 __attribute__((ext_vector_type(4)));
typedef float f32x16 __attribute__((ext_vector_type(16)));

__device__ __forceinline__ short f2bf(float x) {      // RTNE float->bf16 bits
    unsigned u = __float_as_uint(x);
    u += 0x7fffu + ((u >> 16) & 1u);
    return (short)(u >> 16);
}

// ---------------- Kernel 1: normalize -> hi-bf16 fragment tiles + init ap/an ----------------
// Tile layout (per tracklet): slot = (trk*KSTEPS + ks)*64 + lane, 8 bf16 per slot.
// lane l covers frame (l&31), k = ks*16 + (l>>5)*8 + e  (same mapping for A and B; Gram-symmetric).
__global__ __launch_bounds__(64) void norm_kernel(const float* __restrict__ in,
                                                  short* __restrict__ Xhi,
                                                  unsigned* __restrict__ apbuf,
                                                  unsigned* __restrict__ anbuf) {
    const int row = blockIdx.x;      // 0..4095
    const int lane = threadIdx.x;    // one float4 each
    const float4 v = ((const float4*)(in + (size_t)row * DF))[lane];
    float s = v.x*v.x + v.y*v.y + v.z*v.z + v.w*v.w;
    #pragma unroll
    for (int off = 32; off; off >>= 1) s += __shfl_xor(s, off);
    const float inv = 1.0f / fmaxf(sqrtf(s), 1e-12f);
    const float o[4] = {v.x*inv, v.y*inv, v.z*inv, v.w*inv};

    const int trk = row >> 5, r32 = row & 31;
    const int k4 = lane * 4;
    const int ks = k4 >> 4;
    const int kq = k4 & 15;
    const int tl = ((kq >> 3) << 5) | r32;
    const size_t off8 = ((size_t)(trk * KSTEPS + ks) * 64 + tl) * 8 + (kq & 7);

    bf16x4 hv;
    #pragma unroll
    for (int c = 0; c < 4; c++) hv[c] = f2bf(o[c]);
    *(bf16x4*)(Xhi + off8) = hv;

    if (row < NB && lane == 0) {           // init anchor accumulators (runs before pair_kernel)
        apbuf[row] = 0u;                   // max over nonneg d
        anbuf[row] = 0x7F800000u;          // +inf
    }
}

// ---------------- Kernel 2: 2x2 pair-tiles per wave, MFMA + acc-domain epilogue ----------------
__global__ __launch_bounds__(256, 4) void pair_kernel(const short* __restrict__ Xhi,
                                                      const int* __restrict__ tgt,
                                                      unsigned* __restrict__ apbuf,
                                                      unsigned* __restrict__ anbuf) {
    const int w = threadIdx.x >> 6;
    const int l = threadIdx.x & 63;
    const int h = l >> 5;
    const int t32 = l & 31;
    const int wj = blockIdx.x * 4 + w;   // 0..63
    const int wi = blockIdx.y;           // 0..63
    const int i0 = wi * 2, j0 = wj * 2;

    const bf16x8* P  = (const bf16x8*)Xhi;
    const bf16x8* A0 = P + (size_t)i0 * PANEL + l;
    const bf16x8* A1 = A0 + PANEL;
    const bf16x8* B0 = P + (size_t)j0 * PANEL + l;
    const bf16x8* B1 = B0 + PANEL;

    f32x16 acc[4];
    #pragma unroll
    for (int p = 0; p < 4; p++)
        #pragma unroll
        for (int r = 0; r < 16; r++) acc[p][r] = 0.0f;

    #pragma unroll
    for (int ks = 0; ks < KSTEPS; ks++) {
        const bf16x8 a0 = A0[ks * 64];
        const bf16x8 a1 = A1[ks * 64];
        const bf16x8 b0 = B0[ks * 64];
        const bf16x8 b1 = B1[ks * 64];
        acc[0] = __builtin_amdgcn_mfma_f32_32x32x16_bf16(a0, b0, acc[0], 0, 0, 0);
        acc[1] = __builtin_amdgcn_mfma_f32_32x32x16_bf16(a0, b1, acc[1], 0, 0, 0);
        acc[2] = __builtin_amdgcn_mfma_f32_32x32x16_bf16(a1, b0, acc[2], 0, 0, 0);
        acc[3] = __builtin_amdgcn_mfma_f32_32x32x16_bf16(a1, b1, acc[3], 0, 0, 0);
    }

    const int ta0 = tgt[i0], ta1 = tgt[i0 + 1];
    const int tb0 = tgt[j0], tb1 = tgt[j0 + 1];

    // LDS: per-wave private scratch (2-way bank aliasing everywhere = free)
    __shared__ float amat[4][NS][34];
    __shared__ float cnt[4][64];
    __shared__ float kv[4][2];

    // Epilogue fully in acc-domain: d = sqrt(clip(2-2a)) is monotone decreasing,
    // order statistics commute with monotone maps.
    //   dij colmin  <-> colmax(a);  dji rowmin <-> rowmax(a)
    //   K-th largest d <-> K-th smallest a
    //   pos combine max(d) <-> fmin(a);  neg combine min(d) <-> fmax(a)
    #pragma unroll
    for (int pp = 0; pp < 4; pp++) {
        const int ii = i0 + (pp >> 1);
        const int tii = (pp >> 1) ? ta1 : ta0;
        const int tjj = (pp & 1) ? tb1 : tb0;
        const bool pos = (tii == tjj);
        const int K = pos ? 3 : 6;

        // colmax over the 16 in-lane rows, then cross-half swap
        float cm = acc[pp][0];
        #pragma unroll
        for (int r = 1; r < 16; r++) cm = fmaxf(cm, acc[pp][r]);
        cm = fmaxf(cm, __shfl_xor(cm, 32));          // amax_col[t], t=l&31 (dup halves)

        // write a-matrix for row reductions: row=(r&3)+8*(r>>2)+4h, col=l&31
        #pragma unroll
        for (int r = 0; r < 16; r++) {
            const int row = (r & 3) + 8 * (r >> 2) + 4 * h;
            amat[w][row][t32] = acc[pp][r];
        }
        // rowmax: lane reads row (l&31), halves duplicate (broadcast reads)
        float rm = -1e30f;
        #pragma unroll
        for (int k = 0; k < 16; k++) {
            const float2 y = *(const float2*)&amat[w][t32][2 * k];
            rm = fmaxf(rm, fmaxf(y.x, y.y));
        }

        // per-half candidate sets: half0 = colmax set, half1 = rowmax set
        const float x = h ? rm : cm;
        cnt[w][l] = x;
        int c = 0, e = 0;
        const float* cb = &cnt[w][h * 32];
        #pragma unroll
        for (int q = 0; q < 8; q++) {
            const float4 y = *(const float4*)(cb + 4 * q);
            c += (y.x < x) + (y.y < x) + (y.z < x) + (y.w < x);
            e += (y.x == x) + (y.y == x) + (y.z == x) + (y.w == x);
        }
        // K-th smallest a (== K-th largest d) lives here iff c < K <= c+e
        if (c < K && c + e >= K) kv[w][h] = x;

        if (l == 0) {
            const float aij = kv[w][0], aji = kv[w][1];
            const float ac = pos ? fminf(aij, aji) : fmaxf(aij, aji);
            const float d = sqrtf(fmaxf(2.0f - 2.0f * ac, 1e-12f));
            const unsigned ud = __float_as_uint(d);   // d >= 0 -> uint order == float order
            if (pos) atomicMax(&apbuf[ii], ud);
            else     atomicMin(&anbuf[ii], ud);
        }
    }
}

// ---------------- Kernel 3: margin + mean ----------------
__global__ __launch_bounds__(128) void reduce_kernel(const unsigned* __restrict__ apbuf,
                                                     const unsigned* __restrict__ anbuf,
                                                     float* __restrict__ out) {
    const int i = threadIdx.x;   // 0..127
    const float ap = __uint_as_float(apbuf[i]);
    const float an = __uint_as_float(anbuf[i]);
    float li = fmaxf(ap - an + MARGIN, 0.0f);
    #pragma unroll
    for (int off = 32; off; off >>= 1) li += __shfl_xor(li, off);
    __shared__ float ws2[2];
    if ((i & 63) == 0) ws2[i >> 6] = li;
    __syncthreads();
    if (i == 0) out[0] = (ws2[0] + ws2[1]) * (1.0f / (float)NB);
}

extern "C" void kernel_launch(void* const* d_in, const int* in_sizes, int n_in,
                              void* d_out, int out_size, void* d_ws, size_t ws_size,
                              hipStream_t stream) {
    const float* in = (const float*)d_in[0];   // (128,32,256) f32
    const int* tgt = (const int*)d_in[1];      // (128,) i32
    float* out = (float*)d_out;                // scalar

    short* Xhi = (short*)d_ws;                           // 4096*256 bf16 (2 MB)
    unsigned* apbuf = (unsigned*)(Xhi + (size_t)NROW * DF);
    unsigned* anbuf = apbuf + NB;

    norm_kernel<<<NROW, 64, 0, stream>>>(in, Xhi, apbuf, anbuf);
    pair_kernel<<<dim3(16, 64), 256, 0, stream>>>(Xhi, tgt, apbuf, anbuf);
    reduce_kernel<<<1, 128, 0, stream>>>(apbuf, anbuf, out);
}